// Round 3
// baseline (17445.685 us; speedup 1.0000x reference)
//
#include <hip/hip_runtime.h>
#include <math.h>

// ---------------------------------------------------------------------------
// GRUFeatureExtractor — fp32 compute, bf16 bulk storage, ws_size-ADAPTIVE.
// Whole pipeline is chunked over batch (CB rows/chunk); CB picked at launch
// as the largest power-of-two (128..4096) whose arena fits ws_size.
// Arena per chunk (bytes/row): H1 20480 + GO 20480 + union 107008 = 147968.
//   union phase A: P0 P1 GH HCUR XP RL   (layer-0 GRU + preproc)
//   union phase B: GIT GH HCUR           (layer-1 GRU)
//   union phase C: QKV OC AOC AGG HIDB   (attention + head)
// ---------------------------------------------------------------------------

#define SEQ 10

typedef unsigned short bf16u;

__device__ __forceinline__ float b2f(bf16u u) {
    union { unsigned int i; float f; } v; v.i = ((unsigned int)u) << 16; return v.f;
}
__device__ __forceinline__ bf16u f2b(float f) {
    union { float f; unsigned int i; } v; v.f = f;
    unsigned int r = (v.i + 0x7FFFu + ((v.i >> 16) & 1u)) >> 16;
    return (bf16u)r;
}
__device__ __forceinline__ float sigm(float x) { return 1.0f / (1.0f + expf(-x)); }

__global__ void zero_kernel(float* __restrict__ p, int n)
{
    int i = blockIdx.x * 256 + threadIdx.x;
    if (i < n) p[i] = 0.0f;
}

// C[m][n] = sum_k A[m][k] * W[n][k] (+bias[n]) (opt tanh); A dtype TA, C dtype TC.
// W, bias always fp32. blockIdx.z batches with signed per-z element strides.
template <typename TA, typename TC>
__global__ __launch_bounds__(256) void gemm_nt(
    const TA* __restrict__ A, long long sAz, int lda,
    const float* __restrict__ W, long long sWz,
    const float* __restrict__ bias, long long sBz,
    TC* __restrict__ C, long long sCz, int ldc,
    int K, int act)
{
    constexpr int TM = 128, TN = 128, TK = 16, PAD = 4;
    __shared__ float As[TK][TM + PAD];
    __shared__ float Ws[TK][TN + PAD];

    const int z = blockIdx.z;
    A += (long long)z * sAz;
    W += (long long)z * sWz;
    C += (long long)z * sCz;
    const float* bz = bias ? (bias + (long long)z * sBz) : nullptr;

    const int bm = blockIdx.y * TM;
    const int bn = blockIdx.x * TN;
    const int tid = threadIdx.x;
    const int tx = tid & 15;
    const int ty = tid >> 4;

    float acc[8][8];
#pragma unroll
    for (int i = 0; i < 8; ++i)
#pragma unroll
        for (int j = 0; j < 8; ++j) acc[i][j] = 0.0f;

    const int lrow0 = tid >> 2;        // 0..63
    const int lcol  = (tid & 3) * 4;   // 0,4,8,12

    for (int k0 = 0; k0 < K; k0 += TK) {
#pragma unroll
        for (int i = 0; i < 2; ++i) {
            const int row = lrow0 + i * 64;
            const long long aoff = (long long)(bm + row) * lda + (k0 + lcol);
            if constexpr (sizeof(TA) == 4) {
                float4 va = *(const float4*)((const float*)A + aoff);
                As[lcol + 0][row] = va.x; As[lcol + 1][row] = va.y;
                As[lcol + 2][row] = va.z; As[lcol + 3][row] = va.w;
            } else {
                ushort4 va = *(const ushort4*)((const bf16u*)A + aoff);
                As[lcol + 0][row] = b2f(va.x); As[lcol + 1][row] = b2f(va.y);
                As[lcol + 2][row] = b2f(va.z); As[lcol + 3][row] = b2f(va.w);
            }
            float4 vw = *(const float4*)(W + (long long)(bn + row) * K + (k0 + lcol));
            Ws[lcol + 0][row] = vw.x; Ws[lcol + 1][row] = vw.y;
            Ws[lcol + 2][row] = vw.z; Ws[lcol + 3][row] = vw.w;
        }
        __syncthreads();
#pragma unroll
        for (int kk = 0; kk < TK; ++kk) {
            float4 a0 = *(const float4*)&As[kk][ty * 8];
            float4 a1 = *(const float4*)&As[kk][ty * 8 + 4];
            float4 b0 = *(const float4*)&Ws[kk][tx * 8];
            float4 b1 = *(const float4*)&Ws[kk][tx * 8 + 4];
            float av[8] = {a0.x, a0.y, a0.z, a0.w, a1.x, a1.y, a1.z, a1.w};
            float bv[8] = {b0.x, b0.y, b0.z, b0.w, b1.x, b1.y, b1.z, b1.w};
#pragma unroll
            for (int i = 0; i < 8; ++i)
#pragma unroll
                for (int j = 0; j < 8; ++j)
                    acc[i][j] = fmaf(av[i], bv[j], acc[i][j]);
        }
        __syncthreads();
    }

#pragma unroll
    for (int i = 0; i < 8; ++i) {
        const long long row = bm + ty * 8 + i;
        float o[8];
#pragma unroll
        for (int j = 0; j < 8; ++j) {
            float v = acc[i][j];
            if (bz) v += bz[bn + tx * 8 + j];
            if (act) v = tanhf(v);
            o[j] = v;
        }
        if constexpr (sizeof(TC) == 4) {
            float* cp = (float*)C + row * ldc + bn + tx * 8;
            *(float4*)cp       = make_float4(o[0], o[1], o[2], o[3]);
            *(float4*)(cp + 4) = make_float4(o[4], o[5], o[6], o[7]);
        } else {
            bf16u* cp = (bf16u*)C + row * ldc + bn + tx * 8;
            ushort4 u0; u0.x = f2b(o[0]); u0.y = f2b(o[1]); u0.z = f2b(o[2]); u0.w = f2b(o[3]);
            ushort4 u1; u1.x = f2b(o[4]); u1.y = f2b(o[5]); u1.z = f2b(o[6]); u1.w = f2b(o[7]);
            *(ushort4*)cp       = u0;
            *(ushort4*)(cp + 4) = u1;
        }
    }
}

__global__ void roll_kernel(const float* __restrict__ xp, float* __restrict__ rl)
{
    int idx = blockIdx.x * 256 + threadIdx.x;     // CB*512
    int i = idx & 511;
    int b = idx >> 9;
    rl[(size_t)b * 512 + i] = xp[(size_t)b * 512 + ((i + 511) & 511)];
}

// layer0 gate. blockIdx.y = direction d. b is chunk-local (CB rows).
__global__ void gru0_gate(const bf16u* __restrict__ P0, const bf16u* __restrict__ P1,
                          const float* __restrict__ bih, const float* __restrict__ gh,
                          float* __restrict__ hcur, bf16u* __restrict__ h1,
                          int t, int CB)
{
    int idx = blockIdx.x * 256 + threadIdx.x;     // CB*512
    int j = idx & 511;
    int b = idx >> 9;
    int d = blockIdx.y;
    int s = d ? (SEQ - 1 - t) : t;
    float ph = 0.6283185307179586f * (float)s;
    float c0 = 1.0f + 0.1f * cosf(ph);
    float c1 = 0.05f * sinf(ph);

    const bf16u* p0 = P0 + (size_t)b * 3072 + d * 1536;
    const bf16u* p1 = P1 + (size_t)b * 3072 + d * 1536;
    const float* bi = bih + d * 1536;
    const float* g  = gh + ((size_t)d * CB + b) * 1536;
    float* hc = hcur + ((size_t)d * CB + b) * 512;

    float ir  = c0 * b2f(p0[j])        + c1 * b2f(p1[j])        + bi[j];
    float iz  = c0 * b2f(p0[j + 512])  + c1 * b2f(p1[j + 512])  + bi[j + 512];
    float inn = c0 * b2f(p0[j + 1024]) + c1 * b2f(p1[j + 1024]) + bi[j + 1024];
    float hr = g[j], hz = g[j + 512], hn = g[j + 1024];
    float r = sigm(ir + hr);
    float zz = sigm(iz + hz);
    float n = tanhf(inn + r * hn);
    float h = hc[j];
    float hnew = (1.0f - zz) * n + zz * h;
    hc[j] = hnew;
    h1[(size_t)b * (SEQ * 1024) + (size_t)s * 1024 + d * 512 + j] = f2b(hnew);
}

// layer1 gate: gi precomputed fp32 (bias included). blockIdx.y = d.
__global__ void gru1_gate(const float* __restrict__ GIT, const float* __restrict__ gh,
                          float* __restrict__ hcur, bf16u* __restrict__ go,
                          int t, int CB)
{
    int idx = blockIdx.x * 256 + threadIdx.x;     // CB*512
    int j = idx & 511;
    int b = idx >> 9;
    int d = blockIdx.y;
    int s = d ? (SEQ - 1 - t) : t;

    const float* gi = GIT + ((size_t)d * CB + b) * 1536;
    const float* g  = gh  + ((size_t)d * CB + b) * 1536;
    float* hc = hcur + ((size_t)d * CB + b) * 512;

    float ir = gi[j], iz = gi[j + 512], inn = gi[j + 1024];
    float hr = g[j],  hz = g[j + 512],  hn  = g[j + 1024];
    float r = sigm(ir + hr);
    float zz = sigm(iz + hz);
    float n = tanhf(inn + r * hn);
    float h = hc[j];
    float hnew = (1.0f - zz) * n + zz * h;
    hc[j] = hnew;
    go[(size_t)b * (SEQ * 1024) + (size_t)s * 1024 + d * 512 + j] = f2b(hnew);
}

// fused attention per (b_local, head): SEQ=10, HD=128; fp32 math, bf16 I/O
__global__ __launch_bounds__(128) void attn_kernel(const bf16u* __restrict__ qkv,
                                                   bf16u* __restrict__ o)
{
    const int bh = blockIdx.x;
    const int h = bh & 7;
    const int bl = bh >> 3;
    const int tid = threadIdx.x;   // 128

    __shared__ float Q[SEQ][128], Kx[SEQ][128], V[SEQ][128], Amat[SEQ][SEQ];

    const bf16u* base = qkv + (size_t)bl * SEQ * 3072 + h * 128;
#pragma unroll
    for (int s = 0; s < SEQ; ++s) {
        Q[s][tid]  = b2f(base[s * 3072 + tid]);
        Kx[s][tid] = b2f(base[s * 3072 + 1024 + tid]);
        V[s][tid]  = b2f(base[s * 3072 + 2048 + tid]);
    }
    __syncthreads();

    if (tid < SEQ * SEQ) {
        int q = tid / SEQ, k = tid % SEQ;
        float acc = 0.0f;
#pragma unroll 8
        for (int d0 = 0; d0 < 128; ++d0) acc += Q[q][d0] * Kx[k][d0];
        Amat[q][k] = acc * 0.08838834764831845f;   // 1/sqrt(128)
    }
    __syncthreads();

    if (tid < SEQ) {
        float m = -1e30f;
#pragma unroll
        for (int k = 0; k < SEQ; ++k) m = fmaxf(m, Amat[tid][k]);
        float e[SEQ], ssum = 0.0f;
#pragma unroll
        for (int k = 0; k < SEQ; ++k) { e[k] = expf(Amat[tid][k] - m); ssum += e[k]; }
        float inv = 1.0f / ssum;
#pragma unroll
        for (int k = 0; k < SEQ; ++k) Amat[tid][k] = e[k] * inv;
    }
    __syncthreads();

    bf16u* ob = o + (size_t)bl * SEQ * 1024 + h * 128;
#pragma unroll
    for (int q = 0; q < SEQ; ++q) {
        float acc = 0.0f;
#pragma unroll
        for (int k = 0; k < SEQ; ++k) acc += Amat[q][k] * V[k][tid];
        ob[q * 1024 + tid] = f2b(acc);
    }
}

// agg[b][j] = 0.1 * sum_s (gru_out[b][s][j] + attn_out[b][s][j])   (chunk-local)
__global__ void mean_kernel(const bf16u* __restrict__ go, const bf16u* __restrict__ ao,
                            float* __restrict__ agg)
{
    int idx = blockIdx.x * 256 + threadIdx.x;   // CB*1024
    int j = idx & 1023;
    int bl = idx >> 10;
    const bf16u* g = go + (size_t)bl * (SEQ * 1024) + j;
    const bf16u* a = ao + (size_t)bl * (SEQ * 1024) + j;
    float s = 0.0f;
#pragma unroll
    for (int t = 0; t < SEQ; ++t) s += b2f(g[t * 1024]) + b2f(a[t * 1024]);
    agg[(size_t)bl * 1024 + j] = 0.1f * s;
}

extern "C" void kernel_launch(void* const* d_in, const int* in_sizes, int n_in,
                              void* d_out, int out_size, void* d_ws, size_t ws_size,
                              hipStream_t stream)
{
    const float* x    = (const float*)d_in[0];
    const float* Wp   = (const float*)d_in[1];
    const float* bp   = (const float*)d_in[2];
    const float* Wih0 = (const float*)d_in[3];
    const float* Whh0 = (const float*)d_in[4];
    const float* bih0 = (const float*)d_in[5];
    const float* bhh0 = (const float*)d_in[6];
    const float* Wih1 = (const float*)d_in[7];
    const float* Whh1 = (const float*)d_in[8];
    const float* bih1 = (const float*)d_in[9];
    const float* bhh1 = (const float*)d_in[10];
    const float* ipw  = (const float*)d_in[11];
    const float* ipb  = (const float*)d_in[12];
    const float* opw  = (const float*)d_in[13];
    const float* opb  = (const float*)d_in[14];
    const float* W1   = (const float*)d_in[15];
    const float* b1   = (const float*)d_in[16];
    const float* W2   = (const float*)d_in[17];
    const float* b2   = (const float*)d_in[18];
    float* out = (float*)d_out;

    // ---- pick largest chunk CB whose arena fits ws_size (147,968 B/row)
    const long long PER_ROW = 147968LL;
    int CB = 0;
    for (int c = 4096; c >= 128; c >>= 1)
        if ((long long)c * PER_ROW <= (long long)ws_size) { CB = c; break; }
    if (CB == 0) return;   // ws too small — leaves out poisoned (diagnostic)

    // ---- arena layout (all offsets scale with CB; CB>=128 keeps 16B align)
    char* A0 = (char*)d_ws;
    bf16u* H1c = (bf16u*)A0;                        // CB*10240 bf16
    bf16u* GOc = (bf16u*)(A0 + 20480LL * CB);       // CB*10240 bf16
    char*  U   = A0 + 40960LL * CB;
    // phase A
    bf16u* P0   = (bf16u*)U;                        // CB*3072 bf16
    bf16u* P1   = (bf16u*)(U + 6144LL * CB);        // CB*3072 bf16
    float* GH   = (float*)(U + 12288LL * CB);       // 2*CB*1536 f32
    float* HCUR = (float*)(U + 24576LL * CB);       // 2*CB*512 f32
    float* XP   = (float*)(U + 28672LL * CB);       // CB*512 f32
    float* RL   = (float*)(U + 30720LL * CB);       // CB*512 f32
    // phase B (overlays P0/P1)
    float* GIT  = (float*)U;                        // 2*CB*1536 f32
    // phase C (overlays all of U)
    bf16u* QKV  = (bf16u*)U;                        // CB*10*3072 bf16
    bf16u* OC   = (bf16u*)(U + 61440LL * CB);       // CB*10*1024 bf16
    bf16u* AOC  = (bf16u*)(U + 81920LL * CB);       // CB*10*1024 bf16
    float* AGG  = (float*)(U + 102400LL * CB);      // CB*1024 f32
    float* HIDB = (float*)(U + 106496LL * CB);      // CB*128 f32

    const dim3 blk(256);
    const int MB = CB / 128;        // M-tiles per chunk
    const int hcn = 2 * CB * 512;   // HCUR element count

    for (int c0 = 0; c0 < 4096; c0 += CB) {
        // 1) x_proj = x @ Wp^T + bp       (CB,512)
        gemm_nt<float, float><<<dim3(4, MB, 1), blk, 0, stream>>>(
            x + (long long)c0 * 512, 0, 512, Wp, 0, bp, 0, XP, 0, 512, 512, 0);

        // 2) rolled
        roll_kernel<<<CB * 2, blk, 0, stream>>>(XP, RL);

        // 3) P0 = x_proj @ Wih0^T, P1 = rolled @ Wih0^T   (N=3072, both dirs)
        gemm_nt<float, bf16u><<<dim3(24, MB, 1), blk, 0, stream>>>(
            XP, 0, 512, Wih0, 0, nullptr, 0, P0, 0, 3072, 512, 0);
        gemm_nt<float, bf16u><<<dim3(24, MB, 1), blk, 0, stream>>>(
            RL, 0, 512, Wih0, 0, nullptr, 0, P1, 0, 3072, 512, 0);

        // 4) layer-0 biGRU (dirs batched via z; recurrence fp32)
        zero_kernel<<<hcn / 256, blk, 0, stream>>>(HCUR, hcn);
        for (int t = 0; t < SEQ; ++t) {
            gemm_nt<float, float><<<dim3(12, MB, 2), blk, 0, stream>>>(
                HCUR, (long long)CB * 512, 512, Whh0, 1536LL * 512, bhh0, 1536,
                GH, (long long)CB * 1536, 1536, 512, 0);
            gru0_gate<<<dim3(CB * 2, 2), blk, 0, stream>>>(P0, P1, bih0, GH, HCUR, H1c, t, CB);
        }

        // 5) layer-1 biGRU
        zero_kernel<<<hcn / 256, blk, 0, stream>>>(HCUR, hcn);
        for (int t = 0; t < SEQ; ++t) {
            gemm_nt<bf16u, float><<<dim3(12, MB, 2), blk, 0, stream>>>(
                H1c + (long long)t * 1024, (long long)(SEQ - 1 - 2 * t) * 1024, SEQ * 1024,
                Wih1, 1536LL * 1024, bih1, 1536,
                GIT, (long long)CB * 1536, 1536, 1024, 0);
            gemm_nt<float, float><<<dim3(12, MB, 2), blk, 0, stream>>>(
                HCUR, (long long)CB * 512, 512, Whh1, 1536LL * 512, bhh1, 1536,
                GH, (long long)CB * 1536, 1536, 512, 0);
            gru1_gate<<<dim3(CB * 2, 2), blk, 0, stream>>>(GIT, GH, HCUR, GOc, t, CB);
        }

        // 6) attention
        gemm_nt<bf16u, bf16u><<<dim3(24, MB * 10, 1), blk, 0, stream>>>(
            GOc, 0, 1024, ipw, 0, ipb, 0, QKV, 0, 3072, 1024, 0);
        attn_kernel<<<CB * 8, dim3(128), 0, stream>>>(QKV, OC);
        gemm_nt<bf16u, bf16u><<<dim3(8, MB * 10, 1), blk, 0, stream>>>(
            OC, 0, 1024, opw, 0, opb, 0, AOC, 0, 1024, 1024, 0);
        mean_kernel<<<CB * 4, blk, 0, stream>>>(GOc, AOC, AGG);

        // 7) hid = tanh(agg @ W1^T + b1)   (CB,128)
        gemm_nt<float, float><<<dim3(1, MB, 1), blk, 0, stream>>>(
            AGG, 0, 1024, W1, 0, b1, 0, HIDB, 0, 128, 1024, 1);

        // 8) out = hid @ W2^T + b2         (CB,256)
        gemm_nt<float, float><<<dim3(2, MB, 1), blk, 0, stream>>>(
            HIDB, 0, 128, W2, 0, b2, 0, out + (long long)c0 * 256, 0, 256, 128, 0);
    }
}

// Round 4
// 3463.159 us; speedup vs baseline: 5.0375x; 5.0375x over previous
//
#include <hip/hip_runtime.h>
#include <math.h>

// ---------------------------------------------------------------------------
// GRUFeatureExtractor — bf16 MFMA GEMMs (fp32 accum), fp32 gates/recurrence,
// ws_size-ADAPTIVE chunking (CB rows/chunk; phase-C sub-chunked by CBA).
// Weight bf16 copies converted per phase into 2 fixed slots (9.4 MB).
// Layer-0 input proj folded: gi[b,s] = c0[s]*(xp@W^T) + c1[s]*(roll(xp)@W^T).
// ---------------------------------------------------------------------------

#define SEQ 10

typedef unsigned short bf16u;
typedef __attribute__((ext_vector_type(8))) short short8v;   // 8 bf16 (4 VGPR)
typedef __attribute__((ext_vector_type(4))) float f32x4;     // MFMA C/D

__device__ __forceinline__ float b2f(bf16u u) {
    union { unsigned int i; float f; } v; v.i = ((unsigned int)u) << 16; return v.f;
}
__device__ __forceinline__ bf16u f2b(float f) {
    union { float f; unsigned int i; } v; v.f = f;
    unsigned int r = (v.i + 0x7FFFu + ((v.i >> 16) & 1u)) >> 16;
    return (bf16u)r;
}
__device__ __forceinline__ float sigm(float x) { return 1.0f / (1.0f + expf(-x)); }

__global__ void zero_kernel(float* __restrict__ p, int n)
{
    int i = blockIdx.x * 256 + threadIdx.x;
    if (i < n) p[i] = 0.0f;
}

__global__ void cvt_f2b(const float* __restrict__ src, bf16u* __restrict__ dst, int n4)
{
    int i = blockIdx.x * 256 + threadIdx.x;
    if (i < n4) {
        float4 v = ((const float4*)src)[i];
        ushort4 u; u.x = f2b(v.x); u.y = f2b(v.y); u.z = f2b(v.z); u.w = f2b(v.w);
        ((ushort4*)dst)[i] = u;
    }
}

// ---------------------------------------------------------------------------
// MFMA GEMM: C[m][n] = sum_k A[m][k]*W[n][k] (+bias[n]); A,W bf16; acc fp32.
// 128x128 tile, 4 waves (2x2 of 64x64), BK=64, 16x16x32 MFMA.
// LDS linear [128][64] bf16 with XOR swizzle byte^=((row&7)<<4):
// ds_write_b128 and ds_read_b128 both land 2-way (free).
// blockIdx.z batches (signed per-z element strides). M%128==N%128==K%64==0.
// ---------------------------------------------------------------------------
template <typename TC>
__global__ __launch_bounds__(256) void gemm_mfma(
    const bf16u* __restrict__ A, long long sAz, int lda,
    const bf16u* __restrict__ W, long long sWz,
    const float* __restrict__ bias, long long sBz,
    TC* __restrict__ C, long long sCz, int ldc,
    int K, int act)
{
    __shared__ char AsB[128 * 128];   // 128 rows x 64 bf16
    __shared__ char WsB[128 * 128];

    const int z = blockIdx.z;
    A += (long long)z * sAz;
    W += (long long)z * sWz;
    C += (long long)z * sCz;
    const float* bz = bias ? (bias + (long long)z * sBz) : nullptr;

    const int bm = blockIdx.y * 128;
    const int bn = blockIdx.x * 128;
    const int tid = threadIdx.x;
    const int lane = tid & 63;
    const int wave = tid >> 6;
    const int wr = (wave >> 1) * 64;
    const int wc = (wave & 1) * 64;
    const int l15 = lane & 15;
    const int lk8 = (lane >> 4) * 8;      // k sub-offset within 32

    f32x4 acc[4][4];
#pragma unroll
    for (int i = 0; i < 4; ++i)
#pragma unroll
        for (int j = 0; j < 4; ++j)
#pragma unroll
            for (int r = 0; r < 4; ++r) acc[i][j][r] = 0.0f;

    // staging: thread -> row=tid>>1, col base=(tid&1)*8, 4 segments of 8 bf16
    const int srow = tid >> 1;
    const int scol = (tid & 1) << 3;
    const bf16u* Ag = A + (long long)(bm + srow) * lda + scol;
    const bf16u* Wg = W + (long long)(bn + srow) * K + scol;
    int soff[4];
#pragma unroll
    for (int p = 0; p < 4; ++p)
        soff[p] = (srow * 128 + scol * 2 + 32 * p) ^ ((srow & 7) << 4);

    // fragment read offsets (swizzled), per mi/ni and k-half
    int ao[4][2], bo[4][2];
#pragma unroll
    for (int i = 0; i < 4; ++i) {
        int arow = wr + i * 16 + l15;
        int brow = wc + i * 16 + l15;
        int am = (arow & 7) << 4, bm2 = (brow & 7) << 4;
        ao[i][0] = (arow * 128 + lk8 * 2) ^ am;
        ao[i][1] = (arow * 128 + 64 + lk8 * 2) ^ am;
        bo[i][0] = (brow * 128 + lk8 * 2) ^ bm2;
        bo[i][1] = (brow * 128 + 64 + lk8 * 2) ^ bm2;
    }

    for (int k0 = 0; k0 < K; k0 += 64) {
#pragma unroll
        for (int p = 0; p < 4; ++p) {
            float4 va = *(const float4*)(Ag + k0 + 16 * p);
            float4 vw = *(const float4*)(Wg + k0 + 16 * p);
            *(float4*)(AsB + soff[p]) = va;
            *(float4*)(WsB + soff[p]) = vw;
        }
        __syncthreads();
#pragma unroll
        for (int ks = 0; ks < 2; ++ks) {
            short8v af[4], bf[4];
#pragma unroll
            for (int i = 0; i < 4; ++i) af[i] = *(const short8v*)(AsB + ao[i][ks]);
#pragma unroll
            for (int i = 0; i < 4; ++i) bf[i] = *(const short8v*)(WsB + bo[i][ks]);
#pragma unroll
            for (int mi = 0; mi < 4; ++mi)
#pragma unroll
                for (int ni = 0; ni < 4; ++ni)
                    acc[mi][ni] = __builtin_amdgcn_mfma_f32_16x16x32_bf16(
                        af[mi], bf[ni], acc[mi][ni], 0, 0, 0);
        }
        __syncthreads();
    }

    // epilogue: D col=lane&15, row=(lane>>4)*4+r
    const int r0 = (lane >> 4) * 4;
#pragma unroll
    for (int mi = 0; mi < 4; ++mi) {
#pragma unroll
        for (int ni = 0; ni < 4; ++ni) {
            const int col = bn + wc + ni * 16 + l15;
            float badd = bz ? bz[col] : 0.0f;
#pragma unroll
            for (int r = 0; r < 4; ++r) {
                const long long row = bm + wr + mi * 16 + r0 + r;
                float v = acc[mi][ni][r] + badd;
                if (act) v = tanhf(v);
                if constexpr (sizeof(TC) == 4) ((float*)C)[row * ldc + col] = v;
                else                           ((bf16u*)C)[row * ldc + col] = f2b(v);
            }
        }
    }
}

// ---------------------------------------------------------------------------
// fp32 VALU GEMM (kept for x_proj / W1 / W2 — tiny FLOPs, precision-critical)
// ---------------------------------------------------------------------------
__global__ __launch_bounds__(256) void gemm_nt(
    const float* __restrict__ A, int lda,
    const float* __restrict__ W,
    const float* __restrict__ bias,
    float* __restrict__ C, int ldc,
    int K, int act)
{
    constexpr int TK = 16, PAD = 4;
    __shared__ float As[TK][128 + PAD];
    __shared__ float Ws[TK][128 + PAD];

    const int bm = blockIdx.y * 128;
    const int bn = blockIdx.x * 128;
    const int tid = threadIdx.x;
    const int tx = tid & 15;
    const int ty = tid >> 4;

    float acc[8][8];
#pragma unroll
    for (int i = 0; i < 8; ++i)
#pragma unroll
        for (int j = 0; j < 8; ++j) acc[i][j] = 0.0f;

    const int lrow0 = tid >> 2;
    const int lcol  = (tid & 3) * 4;

    for (int k0 = 0; k0 < K; k0 += TK) {
#pragma unroll
        for (int i = 0; i < 2; ++i) {
            const int row = lrow0 + i * 64;
            float4 va = *(const float4*)(A + (long long)(bm + row) * lda + (k0 + lcol));
            As[lcol + 0][row] = va.x; As[lcol + 1][row] = va.y;
            As[lcol + 2][row] = va.z; As[lcol + 3][row] = va.w;
            float4 vw = *(const float4*)(W + (long long)(bn + row) * K + (k0 + lcol));
            Ws[lcol + 0][row] = vw.x; Ws[lcol + 1][row] = vw.y;
            Ws[lcol + 2][row] = vw.z; Ws[lcol + 3][row] = vw.w;
        }
        __syncthreads();
#pragma unroll
        for (int kk = 0; kk < TK; ++kk) {
            float4 a0 = *(const float4*)&As[kk][ty * 8];
            float4 a1 = *(const float4*)&As[kk][ty * 8 + 4];
            float4 b0 = *(const float4*)&Ws[kk][tx * 8];
            float4 b1 = *(const float4*)&Ws[kk][tx * 8 + 4];
            float av[8] = {a0.x, a0.y, a0.z, a0.w, a1.x, a1.y, a1.z, a1.w};
            float bv[8] = {b0.x, b0.y, b0.z, b0.w, b1.x, b1.y, b1.z, b1.w};
#pragma unroll
            for (int i = 0; i < 8; ++i)
#pragma unroll
                for (int j = 0; j < 8; ++j)
                    acc[i][j] = fmaf(av[i], bv[j], acc[i][j]);
        }
        __syncthreads();
    }

#pragma unroll
    for (int i = 0; i < 8; ++i) {
        const long long row = bm + ty * 8 + i;
        float o[8];
#pragma unroll
        for (int j = 0; j < 8; ++j) {
            float v = acc[i][j];
            if (bias) v += bias[bn + tx * 8 + j];
            if (act) v = tanhf(v);
            o[j] = v;
        }
        *(float4*)(C + row * ldc + bn + tx * 8)     = make_float4(o[0], o[1], o[2], o[3]);
        *(float4*)(C + row * ldc + bn + tx * 8 + 4) = make_float4(o[4], o[5], o[6], o[7]);
    }
}

__global__ void roll_kernel(const float* __restrict__ xp, float* __restrict__ rl)
{
    int idx = blockIdx.x * 256 + threadIdx.x;     // CB*512
    int i = idx & 511;
    int b = idx >> 9;
    rl[(size_t)b * 512 + i] = xp[(size_t)b * 512 + ((i + 511) & 511)];
}

// layer0 gate. blockIdx.y = d. Updates HCUR (f32) + HCURb (bf16); writes H1.
__global__ void gru0_gate(const bf16u* __restrict__ P0, const bf16u* __restrict__ P1,
                          const float* __restrict__ bih, const float* __restrict__ gh,
                          float* __restrict__ hcur, bf16u* __restrict__ hcurb,
                          bf16u* __restrict__ h1, int t, int CB)
{
    int idx = blockIdx.x * 256 + threadIdx.x;
    int j = idx & 511;
    int b = idx >> 9;
    int d = blockIdx.y;
    int s = d ? (SEQ - 1 - t) : t;
    float ph = 0.6283185307179586f * (float)s;
    float c0 = 1.0f + 0.1f * cosf(ph);
    float c1 = 0.05f * sinf(ph);

    const bf16u* p0 = P0 + (size_t)b * 3072 + d * 1536;
    const bf16u* p1 = P1 + (size_t)b * 3072 + d * 1536;
    const float* bi = bih + d * 1536;
    const float* g  = gh + ((size_t)d * CB + b) * 1536;
    size_t ho = (size_t)d * CB * 512 + (size_t)b * 512 + j;

    float ir  = c0 * b2f(p0[j])        + c1 * b2f(p1[j])        + bi[j];
    float iz  = c0 * b2f(p0[j + 512])  + c1 * b2f(p1[j + 512])  + bi[j + 512];
    float inn = c0 * b2f(p0[j + 1024]) + c1 * b2f(p1[j + 1024]) + bi[j + 1024];
    float hr = g[j], hz = g[j + 512], hn = g[j + 1024];
    float r = sigm(ir + hr);
    float zz = sigm(iz + hz);
    float n = tanhf(inn + r * hn);
    float hnew = (1.0f - zz) * n + zz * hcur[ho];
    hcur[ho] = hnew;
    hcurb[ho] = f2b(hnew);
    h1[(size_t)b * (SEQ * 1024) + (size_t)s * 1024 + d * 512 + j] = f2b(hnew);
}

__global__ void gru1_gate(const float* __restrict__ GIT, const float* __restrict__ gh,
                          float* __restrict__ hcur, bf16u* __restrict__ hcurb,
                          bf16u* __restrict__ go, int t, int CB)
{
    int idx = blockIdx.x * 256 + threadIdx.x;
    int j = idx & 511;
    int b = idx >> 9;
    int d = blockIdx.y;
    int s = d ? (SEQ - 1 - t) : t;

    const float* gi = GIT + ((size_t)d * CB + b) * 1536;
    const float* g  = gh  + ((size_t)d * CB + b) * 1536;
    size_t ho = (size_t)d * CB * 512 + (size_t)b * 512 + j;

    float ir = gi[j], iz = gi[j + 512], inn = gi[j + 1024];
    float hr = g[j],  hz = g[j + 512],  hn  = g[j + 1024];
    float r = sigm(ir + hr);
    float zz = sigm(iz + hz);
    float n = tanhf(inn + r * hn);
    float hnew = (1.0f - zz) * n + zz * hcur[ho];
    hcur[ho] = hnew;
    hcurb[ho] = f2b(hnew);
    go[(size_t)b * (SEQ * 1024) + (size_t)s * 1024 + d * 512 + j] = f2b(hnew);
}

// fused attention per (b_local, head): SEQ=10, HD=128; fp32 math, bf16 I/O
__global__ __launch_bounds__(128) void attn_kernel(const bf16u* __restrict__ qkv,
                                                   bf16u* __restrict__ o)
{
    const int bh = blockIdx.x;
    const int h = bh & 7;
    const int bl = bh >> 3;
    const int tid = threadIdx.x;

    __shared__ float Q[SEQ][128], Kx[SEQ][128], V[SEQ][128], Amat[SEQ][SEQ];

    const bf16u* base = qkv + (size_t)bl * SEQ * 3072 + h * 128;
#pragma unroll
    for (int s = 0; s < SEQ; ++s) {
        Q[s][tid]  = b2f(base[s * 3072 + tid]);
        Kx[s][tid] = b2f(base[s * 3072 + 1024 + tid]);
        V[s][tid]  = b2f(base[s * 3072 + 2048 + tid]);
    }
    __syncthreads();

    if (tid < SEQ * SEQ) {
        int q = tid / SEQ, k = tid % SEQ;
        float acc = 0.0f;
#pragma unroll 8
        for (int d0 = 0; d0 < 128; ++d0) acc += Q[q][d0] * Kx[k][d0];
        Amat[q][k] = acc * 0.08838834764831845f;
    }
    __syncthreads();

    if (tid < SEQ) {
        float m = -1e30f;
#pragma unroll
        for (int k = 0; k < SEQ; ++k) m = fmaxf(m, Amat[tid][k]);
        float e[SEQ], ssum = 0.0f;
#pragma unroll
        for (int k = 0; k < SEQ; ++k) { e[k] = expf(Amat[tid][k] - m); ssum += e[k]; }
        float inv = 1.0f / ssum;
#pragma unroll
        for (int k = 0; k < SEQ; ++k) Amat[tid][k] = e[k] * inv;
    }
    __syncthreads();

    bf16u* ob = o + (size_t)bl * SEQ * 1024 + h * 128;
#pragma unroll
    for (int q = 0; q < SEQ; ++q) {
        float acc = 0.0f;
#pragma unroll
        for (int k = 0; k < SEQ; ++k) acc += Amat[q][k] * V[k][tid];
        ob[q * 1024 + tid] = f2b(acc);
    }
}

__global__ void mean_kernel(const bf16u* __restrict__ go, const bf16u* __restrict__ ao,
                            float* __restrict__ agg)
{
    int idx = blockIdx.x * 256 + threadIdx.x;   // CBA*1024
    int j = idx & 1023;
    int bl = idx >> 10;
    const bf16u* g = go + (size_t)bl * (SEQ * 1024) + j;
    const bf16u* a = ao + (size_t)bl * (SEQ * 1024) + j;
    float s = 0.0f;
#pragma unroll
    for (int t = 0; t < SEQ; ++t) s += b2f(g[t * 1024]) + b2f(a[t * 1024]);
    agg[(size_t)bl * 1024 + j] = 0.1f * s;
}

extern "C" void kernel_launch(void* const* d_in, const int* in_sizes, int n_in,
                              void* d_out, int out_size, void* d_ws, size_t ws_size,
                              hipStream_t stream)
{
    const float* x    = (const float*)d_in[0];
    const float* Wp   = (const float*)d_in[1];
    const float* bp   = (const float*)d_in[2];
    const float* Wih0 = (const float*)d_in[3];
    const float* Whh0 = (const float*)d_in[4];
    const float* bih0 = (const float*)d_in[5];
    const float* bhh0 = (const float*)d_in[6];
    const float* Wih1 = (const float*)d_in[7];
    const float* Whh1 = (const float*)d_in[8];
    const float* bih1 = (const float*)d_in[9];
    const float* bhh1 = (const float*)d_in[10];
    const float* ipw  = (const float*)d_in[11];
    const float* ipb  = (const float*)d_in[12];
    const float* opw  = (const float*)d_in[13];
    const float* opb  = (const float*)d_in[14];
    const float* W1   = (const float*)d_in[15];
    const float* b1   = (const float*)d_in[16];
    const float* W2   = (const float*)d_in[17];
    const float* b2   = (const float*)d_in[18];
    float* out = (float*)d_out;

    // ---- pick CB / CBA adaptively
    //   weights slots: 9,437,184 B (slotA 3,145,728 el + slotB 1,572,864 el)
    //   per-row: H1 20480 + GO 20480 + union(max(36864, phaseC)) bytes
    const long long WBYTES = 9437184LL;
    int CB = 0, CBA = 0;
    for (int c = 4096; c >= 128; c >>= 1) {
        int ca = (c / 4 < 64) ? 64 : c / 4;
        long long unC = (long long)ca * 102400 + (long long)c * 4608;
        long long unA = (long long)c * 36864;
        long long un = unC > unA ? unC : unA;
        long long tot = WBYTES + (long long)c * 40960 + un;
        if (tot <= (long long)ws_size) { CB = c; CBA = ca; break; }
    }
    if (CB == 0) return;   // ws too small — leaves out poisoned (diagnostic)

    // ---- arena
    bf16u* slotA = (bf16u*)d_ws;                    // up to 3,145,728 el
    bf16u* slotB = slotA + 3145728LL;               // up to 1,572,864 el
    char* A0 = (char*)d_ws + WBYTES;
    bf16u* H1c = (bf16u*)A0;                        // CB*10240 bf16
    bf16u* GOc = (bf16u*)(A0 + 20480LL * CB);       // CB*10240 bf16
    char*  U   = A0 + 40960LL * CB;
    // phase A/B
    bf16u* P0    = (bf16u*)U;                       // CB*3072
    bf16u* P1    = (bf16u*)(U + 6144LL * CB);       // CB*3072
    float* GIT   = (float*)U;                       // 2*CB*1536 (phase B)
    float* GH    = (float*)(U + 12288LL * CB);      // 2*CB*1536
    float* HCUR  = (float*)(U + 24576LL * CB);      // 2*CB*512 f32
    bf16u* HCURb = (bf16u*)(U + 28672LL * CB);      // 2*CB*512 bf16
    float* XP    = (float*)(U + 30720LL * CB);      // CB*512
    float* RL    = (float*)(U + 32768LL * CB);      // CB*512
    bf16u* XPb   = (bf16u*)(U + 34816LL * CB);      // CB*512
    bf16u* RLb   = (bf16u*)(U + 35840LL * CB);      // CB*512
    // phase C (overlays U)
    bf16u* QKV  = (bf16u*)U;                        // CBA*10*3072
    bf16u* OC   = (bf16u*)(U + 61440LL * CBA);      // CBA*10*1024
    bf16u* AOC  = (bf16u*)(U + 81920LL * CBA);      // CBA*10*1024
    float* AGG  = (float*)(U + 102400LL * CBA);     // CB*1024 f32
    float* HIDB = (float*)(U + 102400LL * CBA + 4096LL * CB);  // CB*128 f32

    const dim3 blk(256);
    const int MB = CB / 128;

    for (int c0 = 0; c0 < 4096; c0 += CB) {
        // ---------------- phase A: preproc + layer-0 biGRU ----------------
        gemm_nt<<<dim3(4, MB, 1), blk, 0, stream>>>(
            x + (long long)c0 * 512, 512, Wp, bp, XP, 512, 512, 0);
        roll_kernel<<<CB * 2, blk, 0, stream>>>(XP, RL);
        cvt_f2b<<<CB / 2, blk, 0, stream>>>(XP, XPb, CB * 128);
        cvt_f2b<<<CB / 2, blk, 0, stream>>>(RL, RLb, CB * 128);
        cvt_f2b<<<1536, blk, 0, stream>>>(Wih0, slotA, 393216);
        cvt_f2b<<<1536, blk, 0, stream>>>(Whh0, slotB, 393216);

        gemm_mfma<bf16u><<<dim3(24, MB, 1), blk, 0, stream>>>(
            XPb, 0, 512, slotA, 0, nullptr, 0, P0, 0, 3072, 512, 0);
        gemm_mfma<bf16u><<<dim3(24, MB, 1), blk, 0, stream>>>(
            RLb, 0, 512, slotA, 0, nullptr, 0, P1, 0, 3072, 512, 0);

        zero_kernel<<<CB * 6, blk, 0, stream>>>(HCUR, CB * 1536);  // HCUR+HCURb
        for (int t = 0; t < SEQ; ++t) {
            gemm_mfma<float><<<dim3(12, MB, 2), blk, 0, stream>>>(
                HCURb, (long long)CB * 512, 512, slotB, 1536LL * 512, bhh0, 1536,
                GH, (long long)CB * 1536, 1536, 512, 0);
            gru0_gate<<<dim3(CB * 2, 2), blk, 0, stream>>>(
                P0, P1, bih0, GH, HCUR, HCURb, H1c, t, CB);
        }

        // ---------------- phase B: layer-1 biGRU ----------------
        cvt_f2b<<<3072, blk, 0, stream>>>(Wih1, slotA, 786432);
        cvt_f2b<<<1536, blk, 0, stream>>>(Whh1, slotB, 393216);
        zero_kernel<<<CB * 6, blk, 0, stream>>>(HCUR, CB * 1536);
        for (int t = 0; t < SEQ; ++t) {
            gemm_mfma<float><<<dim3(12, MB, 2), blk, 0, stream>>>(
                H1c + (long long)t * 1024, (long long)(SEQ - 1 - 2 * t) * 1024, SEQ * 1024,
                slotA, 1536LL * 1024, bih1, 1536,
                GIT, (long long)CB * 1536, 1536, 1024, 0);
            gemm_mfma<float><<<dim3(12, MB, 2), blk, 0, stream>>>(
                HCURb, (long long)CB * 512, 512, slotB, 1536LL * 512, bhh1, 1536,
                GH, (long long)CB * 1536, 1536, 512, 0);
            gru1_gate<<<dim3(CB * 2, 2), blk, 0, stream>>>(
                GIT, GH, HCUR, HCURb, GOc, t, CB);
        }

        // ---------------- phase C: attention + head ----------------
        cvt_f2b<<<3072, blk, 0, stream>>>(ipw, slotA, 786432);
        cvt_f2b<<<1024, blk, 0, stream>>>(opw, slotB, 262144);
        for (int a0 = 0; a0 < CB; a0 += CBA) {
            const bf16u* src = GOc + (long long)a0 * 10240;
            gemm_mfma<bf16u><<<dim3(24, CBA * 10 / 128, 1), blk, 0, stream>>>(
                src, 0, 1024, slotA, 0, ipb, 0, QKV, 0, 3072, 1024, 0);
            attn_kernel<<<CBA * 8, dim3(128), 0, stream>>>(QKV, OC);
            gemm_mfma<bf16u><<<dim3(8, CBA * 10 / 128, 1), blk, 0, stream>>>(
                OC, 0, 1024, slotB, 0, opb, 0, AOC, 0, 1024, 1024, 0);
            mean_kernel<<<CBA * 4, blk, 0, stream>>>(src, AOC, AGG + (long long)a0 * 1024);
        }
        gemm_nt<<<dim3(1, MB, 1), blk, 0, stream>>>(
            AGG, 1024, W1, b1, HIDB, 128, 1024, 1);
        gemm_nt<<<dim3(2, MB, 1), blk, 0, stream>>>(
            HIDB, 128, W2, b2, out + (long long)c0 * 256, 256, 128, 0);
    }
}

// Round 7
// 2911.582 us; speedup vs baseline: 5.9918x; 1.1894x over previous
//
#include <hip/hip_runtime.h>
#include <math.h>

// ---------------------------------------------------------------------------
// GRUFeatureExtractor — all GEMMs bf16 MFMA (fp32 accum, global_load_lds
// staging), fp32 gates/recurrence state, ws_size-ADAPTIVE chunking.
//   x(4096,512) -> x_proj -> phase-modulated seq(10) -> biGRU(512) -> biGRU
//   -> 8-head attn over seq=10 -> mean -> tanh MLP -> out(4096,256)
// Layer-0 input proj folded: gi[b,s] = c0[s]*(xp@W^T) + c1[s]*(roll(xp)@W^T).
// Layer-1 input projections batched over all 10 steps in ONE GEMM (GIT bf16).
// R6 bug fixed: weight bf16 region was sized at 1/4 (2.42 MB) — corrected
// conversions overflowed into H1c/GOc. Region restored to 9,437,184 B with
// full-size slots (phase-B max: Wih1b 3,145,728 el + Whh1b 1,572,864 el).
// ---------------------------------------------------------------------------

#define SEQ 10

typedef unsigned short bf16u;
typedef __attribute__((ext_vector_type(8))) short short8v;   // 8 bf16 (4 VGPR)
typedef __attribute__((ext_vector_type(4))) float f32x4;     // MFMA C/D

__device__ __forceinline__ float b2f(bf16u u) {
    union { unsigned int i; float f; } v; v.i = ((unsigned int)u) << 16; return v.f;
}
__device__ __forceinline__ bf16u f2b(float f) {
    union { float f; unsigned int i; } v; v.f = f;
    unsigned int r = (v.i + 0x7FFFu + ((v.i >> 16) & 1u)) >> 16;
    return (bf16u)r;
}
__device__ __forceinline__ float sigm(float x) { return 1.0f / (1.0f + expf(-x)); }

__global__ void zero_kernel(float* __restrict__ p, int n)
{
    int i = blockIdx.x * 256 + threadIdx.x;
    if (i < n) p[i] = 0.0f;
}

__global__ void cvt_f2b(const float* __restrict__ src, bf16u* __restrict__ dst, int n4)
{
    int i = blockIdx.x * 256 + threadIdx.x;
    if (i < n4) {
        float4 v = ((const float4*)src)[i];
        ushort4 u; u.x = f2b(v.x); u.y = f2b(v.y); u.z = f2b(v.z); u.w = f2b(v.w);
        ((ushort4*)dst)[i] = u;
    }
}

// ---------------------------------------------------------------------------
// MFMA GEMM: C[m][n] = sum_k A[m][k]*W[n][k] (+bias[n], opt tanh).
// A,W bf16; acc fp32. 128x128 tile, 4 waves (2x2 of 64x64), BK=64,
// 16x16x32 MFMA, global_load_lds (width 16) into LINEAR LDS [128][64].
// blockIdx.z batches (signed per-z element strides). M%128==N%128==K%64==0.
// ---------------------------------------------------------------------------
template <typename TC>
__global__ __launch_bounds__(256) void gemm_mfma(
    const bf16u* __restrict__ A, long long sAz, int lda,
    const bf16u* __restrict__ W, long long sWz,
    const float* __restrict__ bias, long long sBz,
    TC* __restrict__ C, long long sCz, int ldc,
    int K, int act)
{
    __shared__ bf16u As[128 * 64];
    __shared__ bf16u Ws[128 * 64];

    const int z = blockIdx.z;
    A += (long long)z * sAz;
    W += (long long)z * sWz;
    C += (long long)z * sCz;
    const float* bz = bias ? (bias + (long long)z * sBz) : nullptr;

    const int bm = blockIdx.y * 128;
    const int bn = blockIdx.x * 128;
    const int tid = threadIdx.x;
    const int lane = tid & 63;
    const int wave = tid >> 6;
    const int wr = (wave >> 1) * 64;
    const int wc = (wave & 1) * 64;
    const int l15 = lane & 15;
    const int lk8 = (lane >> 4) * 8;

    f32x4 acc[4][4];
#pragma unroll
    for (int i = 0; i < 4; ++i)
#pragma unroll
        for (int j = 0; j < 4; ++j)
#pragma unroll
            for (int r = 0; r < 4; ++r) acc[i][j][r] = 0.0f;

    // staging: wave w covers rows 32w..32w+31 (4 x gload_lds of 8 rows each);
    // lane i -> row +(i>>3), col elems (i&7)*8.  LDS dest wave-uniform.
    const int sr = wave * 32 + (lane >> 3);
    const int sc = (lane & 7) * 8;
    const bf16u* Ag = A + (long long)(bm + sr) * lda + sc;
    const bf16u* Wg = W + (long long)(bn + sr) * K + sc;
    bf16u* Al = As + wave * 32 * 64;
    bf16u* Wl = Ws + wave * 32 * 64;

    for (int k0 = 0; k0 < K; k0 += 64) {
#pragma unroll
        for (int p = 0; p < 4; ++p) {
            __builtin_amdgcn_global_load_lds(
                (const __attribute__((address_space(1))) void*)(Ag + k0 + (long long)(8 * p) * lda),
                (__attribute__((address_space(3))) void*)(Al + 8 * p * 64), 16, 0, 0);
            __builtin_amdgcn_global_load_lds(
                (const __attribute__((address_space(1))) void*)(Wg + k0 + (long long)(8 * p) * K),
                (__attribute__((address_space(3))) void*)(Wl + 8 * p * 64), 16, 0, 0);
        }
        __syncthreads();
#pragma unroll
        for (int ks = 0; ks < 2; ++ks) {
            short8v af[4], bfr[4];
#pragma unroll
            for (int i = 0; i < 4; ++i)
                af[i] = *(const short8v*)(As + (wr + i * 16 + l15) * 64 + ks * 32 + lk8);
#pragma unroll
            for (int i = 0; i < 4; ++i)
                bfr[i] = *(const short8v*)(Ws + (wc + i * 16 + l15) * 64 + ks * 32 + lk8);
#pragma unroll
            for (int mi = 0; mi < 4; ++mi)
#pragma unroll
                for (int ni = 0; ni < 4; ++ni)
                    acc[mi][ni] = __builtin_amdgcn_mfma_f32_16x16x32_bf16(
                        af[mi], bfr[ni], acc[mi][ni], 0, 0, 0);
        }
        __syncthreads();
    }

    // epilogue: D col=lane&15, row=(lane>>4)*4+r
    const int r0 = (lane >> 4) * 4;
#pragma unroll
    for (int mi = 0; mi < 4; ++mi) {
#pragma unroll
        for (int ni = 0; ni < 4; ++ni) {
            const int col = bn + wc + ni * 16 + l15;
            float badd = bz ? bz[col] : 0.0f;
#pragma unroll
            for (int r = 0; r < 4; ++r) {
                const long long row = bm + wr + mi * 16 + r0 + r;
                float v = acc[mi][ni][r] + badd;
                if (act) v = tanhf(v);
                if constexpr (sizeof(TC) == 4) ((float*)C)[row * ldc + col] = v;
                else                           ((bf16u*)C)[row * ldc + col] = f2b(v);
            }
        }
    }
}

__global__ void roll_b(const bf16u* __restrict__ xp, bf16u* __restrict__ rl)
{
    int idx = blockIdx.x * 256 + threadIdx.x;     // CB*512
    int i = idx & 511;
    int b = idx >> 9;
    rl[(size_t)b * 512 + i] = xp[(size_t)b * 512 + ((i + 511) & 511)];
}

// layer0 gate, 4 elems/thread. blockIdx.y = d. Updates HCUR/HCURb, writes H1.
__global__ void gru0_gate(const bf16u* __restrict__ P0, const bf16u* __restrict__ P1,
                          const float* __restrict__ bih, const float* __restrict__ gh,
                          float* __restrict__ hcur, bf16u* __restrict__ hcurb,
                          bf16u* __restrict__ h1, int t, int CB)
{
    int idx = blockIdx.x * 256 + threadIdx.x;     // CB*128
    int j4 = (idx & 127) * 4;
    int b = idx >> 7;
    int d = blockIdx.y;
    int s = d ? (SEQ - 1 - t) : t;
    float ph = 0.6283185307179586f * (float)s;
    float c0 = 1.0f + 0.1f * cosf(ph);
    float c1 = 0.05f * sinf(ph);

    const bf16u* p0 = P0 + (size_t)b * 3072 + d * 1536 + j4;
    const bf16u* p1 = P1 + (size_t)b * 3072 + d * 1536 + j4;
    const float* bi = bih + d * 1536 + j4;
    const float* g  = gh + ((size_t)d * CB + b) * 1536 + j4;
    size_t ho = ((size_t)d * CB + b) * 512 + j4;

    ushort4 p0r = *(const ushort4*)(p0),        p1r = *(const ushort4*)(p1);
    ushort4 p0z = *(const ushort4*)(p0 + 512),  p1z = *(const ushort4*)(p1 + 512);
    ushort4 p0n = *(const ushort4*)(p0 + 1024), p1n = *(const ushort4*)(p1 + 1024);
    float4 br = *(const float4*)(bi), bzv = *(const float4*)(bi + 512), bn = *(const float4*)(bi + 1024);
    float4 gr = *(const float4*)(g),  gz  = *(const float4*)(g + 512),  gn = *(const float4*)(g + 1024);
    float4 hv = *(const float4*)(hcur + ho);

    float hn4[4]; ushort4 hb;
    {
        float p0a[4] = {b2f(p0r.x), b2f(p0r.y), b2f(p0r.z), b2f(p0r.w)};
        float p1a[4] = {b2f(p1r.x), b2f(p1r.y), b2f(p1r.z), b2f(p1r.w)};
        float p0b[4] = {b2f(p0z.x), b2f(p0z.y), b2f(p0z.z), b2f(p0z.w)};
        float p1b[4] = {b2f(p1z.x), b2f(p1z.y), b2f(p1z.z), b2f(p1z.w)};
        float p0c[4] = {b2f(p0n.x), b2f(p0n.y), b2f(p0n.z), b2f(p0n.w)};
        float p1c[4] = {b2f(p1n.x), b2f(p1n.y), b2f(p1n.z), b2f(p1n.w)};
        float brv[4] = {br.x, br.y, br.z, br.w};
        float bzv2[4] = {bzv.x, bzv.y, bzv.z, bzv.w};
        float bnv[4] = {bn.x, bn.y, bn.z, bn.w};
        float grv[4] = {gr.x, gr.y, gr.z, gr.w};
        float gzv[4] = {gz.x, gz.y, gz.z, gz.w};
        float gnv[4] = {gn.x, gn.y, gn.z, gn.w};
        float hvv[4] = {hv.x, hv.y, hv.z, hv.w};
#pragma unroll
        for (int q = 0; q < 4; ++q) {
            float ir  = c0 * p0a[q] + c1 * p1a[q] + brv[q];
            float iz  = c0 * p0b[q] + c1 * p1b[q] + bzv2[q];
            float inn = c0 * p0c[q] + c1 * p1c[q] + bnv[q];
            float r = sigm(ir + grv[q]);
            float zz = sigm(iz + gzv[q]);
            float n = tanhf(inn + r * gnv[q]);
            hn4[q] = (1.0f - zz) * n + zz * hvv[q];
        }
        hb.x = f2b(hn4[0]); hb.y = f2b(hn4[1]); hb.z = f2b(hn4[2]); hb.w = f2b(hn4[3]);
    }
    *(float4*)(hcur + ho) = make_float4(hn4[0], hn4[1], hn4[2], hn4[3]);
    *(ushort4*)(hcurb + ho) = hb;
    *(ushort4*)(h1 + ((size_t)b * SEQ + s) * 1024 + d * 512 + j4) = hb;
}

// layer1 gate: gi from batched bf16 GIT_all (bias included). 4 elems/thread.
__global__ void gru1_gate(const bf16u* __restrict__ GIT, const float* __restrict__ gh,
                          float* __restrict__ hcur, bf16u* __restrict__ hcurb,
                          bf16u* __restrict__ go, int t, int CB)
{
    int idx = blockIdx.x * 256 + threadIdx.x;     // CB*128
    int j4 = (idx & 127) * 4;
    int b = idx >> 7;
    int d = blockIdx.y;
    int s = d ? (SEQ - 1 - t) : t;

    const bf16u* gi = GIT + ((size_t)d * CB * SEQ + (size_t)b * SEQ + s) * 1536 + j4;
    const float* g  = gh  + ((size_t)d * CB + b) * 1536 + j4;
    size_t ho = ((size_t)d * CB + b) * 512 + j4;

    ushort4 gir = *(const ushort4*)(gi);
    ushort4 giz = *(const ushort4*)(gi + 512);
    ushort4 gin = *(const ushort4*)(gi + 1024);
    float4 gr = *(const float4*)(g), gz = *(const float4*)(g + 512), gn = *(const float4*)(g + 1024);
    float4 hv = *(const float4*)(hcur + ho);

    float ia[4] = {b2f(gir.x), b2f(gir.y), b2f(gir.z), b2f(gir.w)};
    float ib[4] = {b2f(giz.x), b2f(giz.y), b2f(giz.z), b2f(giz.w)};
    float ic[4] = {b2f(gin.x), b2f(gin.y), b2f(gin.z), b2f(gin.w)};
    float grv[4] = {gr.x, gr.y, gr.z, gr.w};
    float gzv[4] = {gz.x, gz.y, gz.z, gz.w};
    float gnv[4] = {gn.x, gn.y, gn.z, gn.w};
    float hvv[4] = {hv.x, hv.y, hv.z, hv.w};
    float hn4[4]; ushort4 hb;
#pragma unroll
    for (int q = 0; q < 4; ++q) {
        float r = sigm(ia[q] + grv[q]);
        float zz = sigm(ib[q] + gzv[q]);
        float n = tanhf(ic[q] + r * gnv[q]);
        hn4[q] = (1.0f - zz) * n + zz * hvv[q];
    }
    hb.x = f2b(hn4[0]); hb.y = f2b(hn4[1]); hb.z = f2b(hn4[2]); hb.w = f2b(hn4[3]);
    *(float4*)(hcur + ho) = make_float4(hn4[0], hn4[1], hn4[2], hn4[3]);
    *(ushort4*)(hcurb + ho) = hb;
    *(ushort4*)(go + ((size_t)b * SEQ + s) * 1024 + d * 512 + j4) = hb;
}

// fused attention per (b_local, head): SEQ=10, HD=128; fp32 math, bf16 I/O
__global__ __launch_bounds__(128) void attn_kernel(const bf16u* __restrict__ qkv,
                                                   bf16u* __restrict__ o)
{
    const int bh = blockIdx.x;
    const int h = bh & 7;
    const int bl = bh >> 3;
    const int tid = threadIdx.x;

    __shared__ float Q[SEQ][128], Kx[SEQ][128], V[SEQ][128], Amat[SEQ][SEQ];

    const bf16u* base = qkv + (size_t)bl * SEQ * 3072 + h * 128;
#pragma unroll
    for (int s = 0; s < SEQ; ++s) {
        Q[s][tid]  = b2f(base[s * 3072 + tid]);
        Kx[s][tid] = b2f(base[s * 3072 + 1024 + tid]);
        V[s][tid]  = b2f(base[s * 3072 + 2048 + tid]);
    }
    __syncthreads();

    if (tid < SEQ * SEQ) {
        int q = tid / SEQ, k = tid % SEQ;
        float acc = 0.0f;
#pragma unroll 8
        for (int d0 = 0; d0 < 128; ++d0) acc += Q[q][d0] * Kx[k][d0];
        Amat[q][k] = acc * 0.08838834764831845f;
    }
    __syncthreads();

    if (tid < SEQ) {
        float m = -1e30f;
#pragma unroll
        for (int k = 0; k < SEQ; ++k) m = fmaxf(m, Amat[tid][k]);
        float e[SEQ], ssum = 0.0f;
#pragma unroll
        for (int k = 0; k < SEQ; ++k) { e[k] = expf(Amat[tid][k] - m); ssum += e[k]; }
        float inv = 1.0f / ssum;
#pragma unroll
        for (int k = 0; k < SEQ; ++k) Amat[tid][k] = e[k] * inv;
    }
    __syncthreads();

    bf16u* ob = o + (size_t)bl * SEQ * 1024 + h * 128;
#pragma unroll
    for (int q = 0; q < SEQ; ++q) {
        float acc = 0.0f;
#pragma unroll
        for (int k = 0; k < SEQ; ++k) acc += Amat[q][k] * V[k][tid];
        ob[q * 1024 + tid] = f2b(acc);
    }
}

// agg_b[b][j] = 0.1 * sum_s (go[b][s][j] + ao[b][s][j]); 4 elems/thread, bf16 out
__global__ void mean_kernel(const bf16u* __restrict__ go, const bf16u* __restrict__ ao,
                            bf16u* __restrict__ agg)
{
    int idx = blockIdx.x * 256 + threadIdx.x;   // CBA*256
    int j4 = (idx & 255) * 4;
    int bl = idx >> 8;
    const bf16u* g = go + (size_t)bl * (SEQ * 1024) + j4;
    const bf16u* a = ao + (size_t)bl * (SEQ * 1024) + j4;
    float s0 = 0, s1 = 0, s2 = 0, s3 = 0;
#pragma unroll
    for (int t = 0; t < SEQ; ++t) {
        ushort4 gv = *(const ushort4*)(g + t * 1024);
        ushort4 av = *(const ushort4*)(a + t * 1024);
        s0 += b2f(gv.x) + b2f(av.x);
        s1 += b2f(gv.y) + b2f(av.y);
        s2 += b2f(gv.z) + b2f(av.z);
        s3 += b2f(gv.w) + b2f(av.w);
    }
    ushort4 u; u.x = f2b(0.1f * s0); u.y = f2b(0.1f * s1); u.z = f2b(0.1f * s2); u.w = f2b(0.1f * s3);
    *(ushort4*)(agg + (size_t)bl * 1024 + j4) = u;
}

extern "C" void kernel_launch(void* const* d_in, const int* in_sizes, int n_in,
                              void* d_out, int out_size, void* d_ws, size_t ws_size,
                              hipStream_t stream)
{
    const float* x    = (const float*)d_in[0];
    const float* Wp   = (const float*)d_in[1];
    const float* bp   = (const float*)d_in[2];
    const float* Wih0 = (const float*)d_in[3];
    const float* Whh0 = (const float*)d_in[4];
    const float* bih0 = (const float*)d_in[5];
    const float* bhh0 = (const float*)d_in[6];
    const float* Wih1 = (const float*)d_in[7];
    const float* Whh1 = (const float*)d_in[8];
    const float* bih1 = (const float*)d_in[9];
    const float* bhh1 = (const float*)d_in[10];
    const float* ipw  = (const float*)d_in[11];
    const float* ipb  = (const float*)d_in[12];
    const float* opw  = (const float*)d_in[13];
    const float* opb  = (const float*)d_in[14];
    const float* W1   = (const float*)d_in[15];
    const float* b1   = (const float*)d_in[16];
    const float* W2   = (const float*)d_in[17];
    const float* b2   = (const float*)d_in[18];
    float* out = (float*)d_out;

    // ---- weight bf16 region: max over phases = 4,718,592 el = 9,437,184 B
    //   phase A: Wp 262,144 + Wih0 1,572,864 + Whh0 1,572,864 = 3,407,872 el
    //   phase B: Wih1 3,145,728 + Whh1 1,572,864            = 4,718,592 el (max)
    //   phase C: ipw 3,145,728 + opw 1,048,576 + W1 131,072 + W2 32,768
    const long long WBYTES = 9437184LL;
    // footprint: WBYTES + CB*40960 (H1,GO) + union (phase B dominates: 79872*CB)
    int CB = 0;
    for (int c = 4096; c >= 128; c >>= 1)
        if (WBYTES + (long long)c * 120832 <= (long long)ws_size) { CB = c; break; }
    if (CB == 0) return;   // ws too small — leaves out poisoned (diagnostic)
    const int CBA = (CB / 4 < 64) ? 64 : CB / 4;

    bf16u* wreg = (bf16u*)d_ws;
    // phase A weights
    bf16u* Wpb   = wreg;                 //   262,144 el
    bf16u* Wih0b = wreg + 262144;        // 1,572,864 el
    bf16u* Whh0b = wreg + 1835008;       // 1,572,864 el (ends 3,407,872)
    // phase B weights (overlay)
    bf16u* Wih1b = wreg;                 // 3,145,728 el
    bf16u* Whh1b = wreg + 3145728;       // 1,572,864 el (ends 4,718,592)
    // phase C weights (overlay)
    bf16u* ipwb  = wreg;                 // 3,145,728 el
    bf16u* opwb  = wreg + 3145728;       // 1,048,576 el
    bf16u* W1b   = wreg + 4194304;       //   131,072 el
    bf16u* W2b   = wreg + 4325376;       //    32,768 el (ends 4,358,144)

    char* A0 = (char*)d_ws + WBYTES;
    bf16u* H1c = (bf16u*)A0;                        // CB*10240
    bf16u* GOc = (bf16u*)(A0 + 20480LL * CB);       // CB*10240
    char*  U   = A0 + 40960LL * CB;
    // phase A
    bf16u* XB    = (bf16u*)U;                       // CB*512
    bf16u* XPb   = (bf16u*)(U + 1024LL * CB);       // CB*512
    bf16u* RLb   = (bf16u*)(U + 2048LL * CB);       // CB*512
    bf16u* P0    = (bf16u*)(U + 3072LL * CB);       // CB*3072
    bf16u* P1    = (bf16u*)(U + 9216LL * CB);       // CB*3072 (P0+CB*3072)
    float* GHa   = (float*)(U + 15360LL * CB);      // 2*CB*1536
    float* HCa   = (float*)(U + 27648LL * CB);      // 2*CB*512 f32
    bf16u* HCab  = (bf16u*)(U + 31744LL * CB);      // 2*CB*512 bf16
    // phase B (overlays A)
    bf16u* GIT   = (bf16u*)U;                       // 2*CB*10*1536
    float* GHb   = (float*)(U + 61440LL * CB);
    float* HCb   = (float*)(U + 73728LL * CB);
    bf16u* HCbb  = (bf16u*)(U + 77824LL * CB);
    // phase C (overlays A/B)
    bf16u* QKV   = (bf16u*)U;                       // CBA*10*3072
    bf16u* OC    = (bf16u*)(U + 61440LL * CBA);     // CBA*10*1024
    bf16u* AOC   = (bf16u*)(U + 81920LL * CBA);     // CBA*10*1024
    bf16u* AGGb  = (bf16u*)(U + 102400LL * CBA);    // CB*1024
    bf16u* HIDb  = (bf16u*)(U + 102400LL * CBA + 2048LL * CB);  // CB*128

    const dim3 blk(256);
    const int MB = CB / 128;

    // derived-size weight conversion
    auto cvt = [&](const float* s, bf16u* d, long long nfloats) {
        int n4 = (int)(nfloats / 4);
        cvt_f2b<<<(n4 + 255) / 256, blk, 0, stream>>>(s, d, n4);
    };

    for (int c0 = 0; c0 < 4096; c0 += CB) {
        // ---------------- phase A: preproc + layer-0 biGRU ----------------
        cvt(x + (long long)c0 * 512, XB, (long long)CB * 512);
        cvt(Wp,   Wpb,   512LL * 512);            //   262,144
        cvt(Wih0, Wih0b, 2LL * 1536 * 512);       // 1,572,864
        cvt(Whh0, Whh0b, 2LL * 1536 * 512);       // 1,572,864

        gemm_mfma<bf16u><<<dim3(4, MB, 1), blk, 0, stream>>>(
            XB, 0, 512, Wpb, 0, bp, 0, XPb, 0, 512, 512, 0);
        roll_b<<<CB * 2, blk, 0, stream>>>(XPb, RLb);
        // P0,P1 batched via z (XPb/RLb and P0/P1 contiguous)
        gemm_mfma<bf16u><<<dim3(24, MB, 2), blk, 0, stream>>>(
            XPb, (long long)CB * 512, 512, Wih0b, 0, nullptr, 0,
            P0, (long long)CB * 3072, 3072, 512, 0);

        zero_kernel<<<CB * 6, blk, 0, stream>>>(HCa, CB * 1536);  // HCUR+HCURb
        for (int t = 0; t < SEQ; ++t) {
            gemm_mfma<float><<<dim3(12, MB, 2), blk, 0, stream>>>(
                HCab, (long long)CB * 512, 512, Whh0b, 1536LL * 512, bhh0, 1536,
                GHa, (long long)CB * 1536, 1536, 512, 0);
            gru0_gate<<<dim3(CB / 2, 2), blk, 0, stream>>>(
                P0, P1, bih0, GHa, HCa, HCab, H1c, t, CB);
        }

        // ---------------- phase B: layer-1 biGRU ----------------
        cvt(Wih1, Wih1b, 2LL * 1536 * 1024);      // 3,145,728
        cvt(Whh1, Whh1b, 2LL * 1536 * 512);       // 1,572,864
        // ALL 10 input projections in one GEMM: M=CB*10, N=1536, K=1024, z=2
        gemm_mfma<bf16u><<<dim3(12, MB * 10, 2), blk, 0, stream>>>(
            H1c, 0, 1024, Wih1b, 1536LL * 1024, bih1, 1536,
            GIT, (long long)CB * SEQ * 1536, 1536, 1024, 0);

        zero_kernel<<<CB * 6, blk, 0, stream>>>(HCb, CB * 1536);
        for (int t = 0; t < SEQ; ++t) {
            gemm_mfma<float><<<dim3(12, MB, 2), blk, 0, stream>>>(
                HCbb, (long long)CB * 512, 512, Whh1b, 1536LL * 512, bhh1, 1536,
                GHb, (long long)CB * 1536, 1536, 512, 0);
            gru1_gate<<<dim3(CB / 2, 2), blk, 0, stream>>>(
                GIT, GHb, HCb, HCbb, GOc, t, CB);
        }

        // ---------------- phase C: attention + head ----------------
        cvt(ipw, ipwb, 3072LL * 1024);            // 3,145,728
        cvt(opw, opwb, 1024LL * 1024);            // 1,048,576
        cvt(W1,  W1b,  128LL * 1024);             //   131,072
        cvt(W2,  W2b,  256LL * 128);              //    32,768
        for (int a0 = 0; a0 < CB; a0 += CBA) {
            const bf16u* src = GOc + (long long)a0 * 10240;
            gemm_mfma<bf16u><<<dim3(24, CBA * 10 / 128, 1), blk, 0, stream>>>(
                src, 0, 1024, ipwb, 0, ipb, 0, QKV, 0, 3072, 1024, 0);
            attn_kernel<<<CBA * 8, dim3(128), 0, stream>>>(QKV, OC);
            gemm_mfma<bf16u><<<dim3(8, CBA * 10 / 128, 1), blk, 0, stream>>>(
                OC, 0, 1024, opwb, 0, opb, 0, AOC, 0, 1024, 1024, 0);
            mean_kernel<<<CBA, blk, 0, stream>>>(src, AOC, AGGb + (long long)a0 * 1024);
        }
        gemm_mfma<bf16u><<<dim3(1, MB, 1), blk, 0, stream>>>(
            AGGb, 0, 1024, W1b, 0, b1, 0, HIDb, 0, 128, 1024, 1);
        gemm_mfma<float><<<dim3(2, MB, 1), blk, 0, stream>>>(
            HIDb, 0, 128, W2b, 0, b2, 0, out + (long long)c0 * 256, 0, 256, 128, 0);
    }
}